// Round 1
// baseline (1812.907 us; speedup 1.0000x reference)
//
#include <hip/hip_runtime.h>
#include <math.h>

#define NN 50000
#define NE 800000
#define FD 128
#define EDD 32
#define NG 64
#define NA 16
#define EPSV 1e-5f

__device__ __forceinline__ float sigf(float v) { return 1.0f / (1.0f + __expf(-v)); }

// ---- edge stage: agg[dst] += relu(x[src] + ea @ We^T + be) ----------------
// 128 threads per edge (c = t&127); We row in registers; ea via uniform float4.
__global__ __launch_bounds__(256) void edge_kernel(
    const float* __restrict__ xin, const float* __restrict__ eattr,
    const int* __restrict__ ei, const float* __restrict__ We,
    const float* __restrict__ be, float* __restrict__ agg)
{
    const int t = threadIdx.x;
    const int c = t & 127;
    const int lr = t >> 7;
    float w[32];
    {
        const float4* wv = (const float4*)(We + c * EDD);
#pragma unroll
        for (int i = 0; i < 8; ++i) {
            float4 v = wv[i];
            w[4 * i + 0] = v.x; w[4 * i + 1] = v.y;
            w[4 * i + 2] = v.z; w[4 * i + 3] = v.w;
        }
    }
    const float bec = be[c];
    const int e0 = blockIdx.x * 32;
#pragma unroll 2
    for (int ie = lr; ie < 32; ie += 2) {
        const int e = e0 + ie;
        const int src = ei[e];
        const int dst = ei[NE + e];
        const float4* ev = (const float4*)(eattr + (long)e * EDD);
        float acc = bec;
#pragma unroll
        for (int i = 0; i < 8; ++i) {
            float4 v = ev[i];
            acc = fmaf(v.x, w[4 * i + 0], acc);
            acc = fmaf(v.y, w[4 * i + 1], acc);
            acc = fmaf(v.z, w[4 * i + 2], acc);
            acc = fmaf(v.w, w[4 * i + 3], acc);
        }
        float m = acc + xin[(long)src * FD + c];
        m = fmaxf(m, 0.0f);
        atomicAdd(agg + (long)dst * FD + c, m);
    }
}

// ---- node GEMM: hpre = (xin + agg) @ W^T + b, fused BN column stats -------
__global__ __launch_bounds__(256) void node_kernel(
    const float* __restrict__ xin, const float* __restrict__ agg,
    const float* __restrict__ W, const float* __restrict__ b,
    float* __restrict__ hpre, float* __restrict__ colsum, float* __restrict__ colsq)
{
    __shared__ float rowJ[8 * 132];   // [row j][k], +4 pad
    __shared__ float red[256];
    const int t = threadIdx.x;
    const int c = t & 127;
    const int half = t >> 7;
    const int js = t & 7;      // staging: row
    const int kk = t >> 3;     // staging: k-chunk 0..31
    const float bc = b[c];
    const float4* wp = (const float4*)(W + c * FD);
    float s1 = 0.0f, s2 = 0.0f;
    const int stride = gridDim.x * 8;
    const int iters = (NN + stride - 1) / stride;   // uniform across blocks
    for (int it = 0; it < iters; ++it) {
        const int r0 = (blockIdx.x + it * gridDim.x) * 8;
        __syncthreads();
        {
            const int r = r0 + js;
            float4 v = make_float4(0.f, 0.f, 0.f, 0.f);
            if (r < NN) {
                const float4 xv = *(const float4*)(xin + (long)r * FD + kk * 4);
                const float4 av = *(const float4*)(agg + (long)r * FD + kk * 4);
                v = make_float4(xv.x + av.x, xv.y + av.y, xv.z + av.z, xv.w + av.w);
            }
            *(float4*)(&rowJ[js * 132 + kk * 4]) = v;
        }
        __syncthreads();
        float a0 = 0.f, a1 = 0.f, a2 = 0.f, a3 = 0.f;
        const int jb = half * 4;
#pragma unroll 8
        for (int k4 = 0; k4 < 32; ++k4) {
            const float4 w4 = wp[k4];
            const float4 r0v = *(const float4*)(&rowJ[(jb + 0) * 132 + k4 * 4]);
            const float4 r1v = *(const float4*)(&rowJ[(jb + 1) * 132 + k4 * 4]);
            const float4 r2v = *(const float4*)(&rowJ[(jb + 2) * 132 + k4 * 4]);
            const float4 r3v = *(const float4*)(&rowJ[(jb + 3) * 132 + k4 * 4]);
            a0 += w4.x * r0v.x + w4.y * r0v.y + w4.z * r0v.z + w4.w * r0v.w;
            a1 += w4.x * r1v.x + w4.y * r1v.y + w4.z * r1v.z + w4.w * r1v.w;
            a2 += w4.x * r2v.x + w4.y * r2v.y + w4.z * r2v.z + w4.w * r2v.w;
            a3 += w4.x * r3v.x + w4.y * r3v.y + w4.z * r3v.z + w4.w * r3v.w;
        }
        const float vals[4] = { a0 + bc, a1 + bc, a2 + bc, a3 + bc };
#pragma unroll
        for (int j2 = 0; j2 < 4; ++j2) {
            const int rr = r0 + jb + j2;
            if (rr < NN) {
                hpre[(long)rr * FD + c] = vals[j2];
                s1 += vals[j2];
                s2 += vals[j2] * vals[j2];
            }
        }
    }
    red[t] = s1;
    __syncthreads();
    float S1 = 0.f;
    if (t < 128) S1 = red[t] + red[t + 128];
    __syncthreads();
    red[t] = s2;
    __syncthreads();
    if (t < 128) {
        const float S2 = red[t] + red[t + 128];
        atomicAdd(&colsum[c], S1);
        atomicAdd(&colsq[c], S2);
    }
}

// ---- BN finalize + relu (layer 1) ----------------------------------------
__global__ __launch_bounds__(256) void norm_relu_kernel(
    const float* __restrict__ hpre, const float* __restrict__ cs,
    const float* __restrict__ cq, const float* __restrict__ ga,
    const float* __restrict__ bb, float* __restrict__ hout)
{
    const long base = ((long)blockIdx.x * 256 + threadIdx.x) * 4;
    const int c0 = (int)(base & 127);
    const float invN = 1.0f / (float)NN;
    const float4 v = *(const float4*)(hpre + base);
    const float4 s = *(const float4*)(cs + c0);
    const float4 q = *(const float4*)(cq + c0);
    const float4 g = *(const float4*)(ga + c0);
    const float4 be = *(const float4*)(bb + c0);
    float4 o;
    { const float m = s.x * invN; const float iv = rsqrtf(q.x * invN - m * m + EPSV);
      o.x = fmaxf((v.x - m) * iv * g.x + be.x, 0.f); }
    { const float m = s.y * invN; const float iv = rsqrtf(q.y * invN - m * m + EPSV);
      o.y = fmaxf((v.y - m) * iv * g.y + be.y, 0.f); }
    { const float m = s.z * invN; const float iv = rsqrtf(q.z * invN - m * m + EPSV);
      o.z = fmaxf((v.z - m) * iv * g.z + be.z, 0.f); }
    { const float m = s.w * invN; const float iv = rsqrtf(q.w * invN - m * m + EPSV);
      o.w = fmaxf((v.w - m) * iv * g.w + be.w, 0.f); }
    *(float4*)(hout + base) = o;
}

// ---- BN finalize + relu + sigmoid + per-graph pooled sums (layer 2) ------
__global__ __launch_bounds__(256) void norm_pool_kernel(
    const float* __restrict__ hpre, const float* __restrict__ cs,
    const float* __restrict__ cq, const float* __restrict__ ga,
    const float* __restrict__ bb, const int* __restrict__ batch,
    float* __restrict__ pooled)
{
    __shared__ float pl[NG * FD];
    const int t = threadIdx.x;
    const int c = t & 127;
    const int half = t >> 7;
    const int r0 = blockIdx.x * 128;
    const int rend = min(r0 + 128, NN);
    const int gmin = batch[r0];
    const int gmax = batch[rend - 1];   // batch is sorted
    const int span = gmax - gmin + 1;
    for (int i = t; i < span * FD; i += 256) pl[i] = 0.f;
    __syncthreads();
    const float invN = 1.0f / (float)NN;
    const float m = cs[c] * invN;
    const float iv = rsqrtf(cq[c] * invN - m * m + EPSV);
    const float gg = ga[c];
    const float bt = bb[c];
    for (int ir = half; ir < 128; ir += 2) {
        const int r = r0 + ir;
        if (r >= rend) break;
        float v = (hpre[(long)r * FD + c] - m) * iv * gg + bt;
        v = sigf(fmaxf(v, 0.f));
        atomicAdd(&pl[(batch[r] - gmin) * FD + c], v);
    }
    __syncthreads();
    for (int i = t; i < span * FD; i += 256) atomicAdd(&pooled[gmin * FD + i], pl[i]);
}

__device__ __forceinline__ int lbound(const int* __restrict__ a, int n, int v)
{
    int lo = 0, hi = n;
    while (lo < hi) { const int mid = (lo + hi) >> 1; if (a[mid] < v) lo = mid + 1; else hi = mid; }
    return lo;
}

// ---- action MLP head, single block ---------------------------------------
__global__ __launch_bounds__(256) void mlp_kernel(
    const float* __restrict__ pooled, const int* __restrict__ batch,
    const float* __restrict__ A1w, const float* __restrict__ A1b,
    const float* __restrict__ Ag1, const float* __restrict__ Ab1,
    const float* __restrict__ A2w, const float* __restrict__ A2b,
    const float* __restrict__ Ag2, const float* __restrict__ Ab2,
    const float* __restrict__ A3w, const float* __restrict__ A3b,
    float* __restrict__ out)
{
    __shared__ float Z[NG * FD];
    __shared__ float red[256];
    __shared__ float ml[128], il[128];
    __shared__ float cr[NG];
    const int t = threadIdx.x;
    const int c = t & 127;
    const int half = t >> 7;
    if (t < NG) {
        const int lo = lbound(batch, NN, t);
        const int hi = lbound(batch, NN, t + 1);
        cr[t] = 1.0f / fmaxf((float)(hi - lo), 1.0f);
    }
    __syncthreads();
    float z[32];
    float s1 = 0.f, s2 = 0.f;
    // layer 1 (reads global pooled sums, scales by 1/count)
    {
        const float bc = A1b[c];
        const float4* wp = (const float4*)(A1w + c * FD);
        for (int ii = 0; ii < 32; ++ii) {
            const int gi = half + 2 * ii;
            const float4* pp = (const float4*)(pooled + gi * FD);
            float d = 0.f;
#pragma unroll 8
            for (int k4 = 0; k4 < 32; ++k4) {
                const float4 w4 = wp[k4];
                const float4 p4 = pp[k4];
                d += w4.x * p4.x + w4.y * p4.y + w4.z * p4.z + w4.w * p4.w;
            }
            const float a = fmaf(d, cr[gi], bc);
            z[ii] = a; s1 += a; s2 += a * a;
        }
    }
    red[t] = s1; __syncthreads();
    if (t < 128) ml[c] = (red[t] + red[t + 128]) * (1.0f / NG);
    __syncthreads();
    red[t] = s2; __syncthreads();
    if (t < 128) {
        const float ms = (red[t] + red[t + 128]) * (1.0f / NG);
        const float mm = ml[c];
        il[c] = rsqrtf(ms - mm * mm + EPSV);
    }
    __syncthreads();
    {
        const float mm = ml[c], iv = il[c], gg = Ag1[c], bb = Ab1[c];
        for (int ii = 0; ii < 32; ++ii) {
            const int gi = half + 2 * ii;
            Z[gi * FD + c] = fmaxf((z[ii] - mm) * iv * gg + bb, 0.f);
        }
    }
    __syncthreads();
    // layer 2 (reads Z)
    s1 = 0.f; s2 = 0.f;
    {
        const float bc = A2b[c];
        const float4* wp = (const float4*)(A2w + c * FD);
        for (int ii = 0; ii < 32; ++ii) {
            const int gi = half + 2 * ii;
            const float4* pp = (const float4*)(&Z[gi * FD]);
            float d = bc;
#pragma unroll 8
            for (int k4 = 0; k4 < 32; ++k4) {
                const float4 w4 = wp[k4];
                const float4 p4 = pp[k4];
                d += w4.x * p4.x + w4.y * p4.y + w4.z * p4.z + w4.w * p4.w;
            }
            z[ii] = d; s1 += d; s2 += d * d;
        }
    }
    red[t] = s1; __syncthreads();
    if (t < 128) ml[c] = (red[t] + red[t + 128]) * (1.0f / NG);
    __syncthreads();
    red[t] = s2; __syncthreads();
    if (t < 128) {
        const float ms = (red[t] + red[t + 128]) * (1.0f / NG);
        const float mm = ml[c];
        il[c] = rsqrtf(ms - mm * mm + EPSV);
    }
    __syncthreads();   // also guarantees all layer-2 reads of Z are done
    {
        const float mm = ml[c], iv = il[c], gg = Ag2[c], bb = Ab2[c];
        for (int ii = 0; ii < 32; ++ii) {
            const int gi = half + 2 * ii;
            Z[gi * FD + c] = fmaxf((z[ii] - mm) * iv * gg + bb, 0.f);
        }
    }
    __syncthreads();
    // layer 3 + sigmoid
    for (int i = t; i < NG * NA; i += 256) {
        const int gi = i >> 4;
        const int a = i & 15;
        const float4* wp = (const float4*)(A3w + a * FD);
        const float4* pp = (const float4*)(&Z[gi * FD]);
        float d = A3b[a];
#pragma unroll 8
        for (int k4 = 0; k4 < 32; ++k4) {
            const float4 w4 = wp[k4];
            const float4 p4 = pp[k4];
            d += w4.x * p4.x + w4.y * p4.y + w4.z * p4.z + w4.w * p4.w;
        }
        out[i] = sigf(d);
    }
}

extern "C" void kernel_launch(void* const* d_in, const int* in_sizes, int n_in,
                              void* d_out, int out_size, void* d_ws, size_t ws_size,
                              hipStream_t stream)
{
    const float* x     = (const float*)d_in[0];
    const float* ea    = (const float*)d_in[1];
    const int*   ei    = (const int*)d_in[2];
    const int*   batch = (const int*)d_in[3];
    const float* W1  = (const float*)d_in[4];
    const float* b1  = (const float*)d_in[5];
    const float* We1 = (const float*)d_in[6];
    const float* be1 = (const float*)d_in[7];
    const float* g1  = (const float*)d_in[8];
    const float* bt1 = (const float*)d_in[9];
    const float* W2  = (const float*)d_in[10];
    const float* b2  = (const float*)d_in[11];
    const float* We2 = (const float*)d_in[12];
    const float* be2 = (const float*)d_in[13];
    const float* g2  = (const float*)d_in[14];
    const float* bt2 = (const float*)d_in[15];
    const float* A1w = (const float*)d_in[16];
    const float* A1b = (const float*)d_in[17];
    const float* Ag1 = (const float*)d_in[18];
    const float* Ab1 = (const float*)d_in[19];
    const float* A2w = (const float*)d_in[20];
    const float* A2b = (const float*)d_in[21];
    const float* Ag2 = (const float*)d_in[22];
    const float* Ab2 = (const float*)d_in[23];
    const float* A3w = (const float*)d_in[24];
    const float* A3b = (const float*)d_in[25];
    float* out = (float*)d_out;

    float* ws      = (float*)d_ws;
    float* agg     = ws;                     // [NN*FD]
    float* hpre    = ws + (long)NN * FD;     // [NN*FD]
    float* h1      = ws + 2L * NN * FD;      // [NN*FD]
    float* stats   = ws + 3L * NN * FD;      // 512 + NG*FD floats
    float* colsum1 = stats;
    float* colsq1  = stats + 128;
    float* colsum2 = stats + 256;
    float* colsq2  = stats + 384;
    float* pooled  = stats + 512;

    hipMemsetAsync(agg, 0, (size_t)NN * FD * sizeof(float), stream);
    hipMemsetAsync(stats, 0, (512 + NG * FD) * sizeof(float), stream);
    edge_kernel<<<NE / 32, 256, 0, stream>>>(x, ea, ei, We1, be1, agg);
    node_kernel<<<512, 256, 0, stream>>>(x, agg, W1, b1, hpre, colsum1, colsq1);
    norm_relu_kernel<<<(NN * FD) / 1024, 256, 0, stream>>>(hpre, colsum1, colsq1, g1, bt1, h1);
    hipMemsetAsync(agg, 0, (size_t)NN * FD * sizeof(float), stream);
    edge_kernel<<<NE / 32, 256, 0, stream>>>(h1, ea, ei, We2, be2, agg);
    node_kernel<<<512, 256, 0, stream>>>(h1, agg, W2, b2, hpre, colsum2, colsq2);
    norm_pool_kernel<<<(NN + 127) / 128, 256, 0, stream>>>(hpre, colsum2, colsq2, g2, bt2, batch, pooled);
    mlp_kernel<<<1, 256, 0, stream>>>(pooled, batch, A1w, A1b, Ag1, Ab1,
                                      A2w, A2b, Ag2, Ab2, A3w, A3b, out);
}